// Round 3
// baseline (221.798 us; speedup 1.0000x reference)
//
#include <hip/hip_runtime.h>
#include <math.h>

// Problem constants
#define NB    4096   // batch
#define NCEN  2048   // centres
#define DX    32     // feature dim
#define SEG   512    // centres per segment
#define RK    64     // TT rank
#define CAP   64     // max kept centres per (b, segment)
#define NBCAP (NB * CAP)
#define NCH   64     // b-chunks of 64 rows each (two-level scatter scan)
#define CHUNK 64     // entries per inv_stage work item
#define QMAX  (NBCAP / CHUNK + SEG)   // 4608 max chunks per segment

typedef unsigned short us8 __attribute__((ext_vector_type(8)));
typedef short bfrag __attribute__((ext_vector_type(8)));
typedef float f32x4 __attribute__((ext_vector_type(4)));

static __device__ __forceinline__ int wave_sum_i(int v) {
    v += __shfl_xor(v, 1);  v += __shfl_xor(v, 2);  v += __shfl_xor(v, 4);
    v += __shfl_xor(v, 8);  v += __shfl_xor(v, 16); v += __shfl_xor(v, 32);
    return v;
}
static __device__ __forceinline__ float wave_min_f(float v) {
    v = fminf(v, __shfl_xor(v, 1));  v = fminf(v, __shfl_xor(v, 2));
    v = fminf(v, __shfl_xor(v, 4));  v = fminf(v, __shfl_xor(v, 8));
    v = fminf(v, __shfl_xor(v, 16)); v = fminf(v, __shfl_xor(v, 32));
    return v;
}
// bf16 pack/unpack (RNE — truncation would bias coherently, RNE stays
// incoherent across terms). bf16 keeps fp32 exponent range.
static __device__ __forceinline__ unsigned short f2bf(float f) {
    unsigned u = __float_as_uint(f);
    u += 0x7FFFu + ((u >> 16) & 1u);
    return (unsigned short)(u >> 16);
}
static __device__ __forceinline__ float bf2f(unsigned short h) {
    return __uint_as_float(((unsigned)h) << 16);
}
// async global->LDS DMA, 16B per lane. LDS dest is wave-uniform base;
// global src is per-lane (guide §5, m97/m03).
static __device__ __forceinline__ void async_copy16(const void* g, void* l) {
    __builtin_amdgcn_global_load_lds(
        (const __attribute__((address_space(1))) unsigned int*)g,
        (__attribute__((address_space(3))) unsigned int*)l, 16, 0, 0);
}

// ---------------------------------------------------------------------------
// select_fused: e_gemm + rowselect in one kernel — E never touches memory.
// Block = (seg, chunk of 64 b's); grid 256 = 1 block/CU, single round.
// Each LANE computes E for its own select assignment d = lane*8+q; 8 rows
// per register batch (acc[8][8], FMA-bound). C strip staged with per-row
// 16B-chunk rotation cc=(c+(d>>3))&7 -> conflict-free ds_read_b128 (the
// rotation index equals the reading lane). HIST2 becomes block-local (block
// == one [seg][chunk] slice): LDS histogram + plain stores, no global
// atomics, no pre-zero pass. All E/xn/cni FMAs in original sequential
// k-order; R0's reduction tree replicated group-exactly -> bit-identical.
// ---------------------------------------------------------------------------
__global__ __launch_bounds__(256) void select_fused(
    const float* __restrict__ X, const float* __restrict__ C,
    const float* __restrict__ LS, const float* __restrict__ G0,
    int* __restrict__ CNT, int* __restrict__ IDX, float* __restrict__ VAL,
    int* __restrict__ HIST2, float* __restrict__ R0v)
{
    __shared__ float  CT[SEG * 32];        // rotated chunks, 64 KB
    __shared__ float  XT[64 * 32];         // 8 KB
    __shared__ float  xn[64];
    __shared__ float2 cni[SEG];            // 4 KB
    __shared__ int    hist[SEG];           // 2 KB
    __shared__ int    rcnt[64];
    __shared__ int    sdv[64 * CAP];       // seg0 only: kept d per row/slot (16 KB)
    __shared__ float  svv[64 * CAP];       // seg0 only: exp(-e) (16 KB)

    const int tid = threadIdx.x;
    const int chunk = (int)blockIdx.x;     // b-group of 64
    const int seg = (int)blockIdx.y;
    const int b0 = chunk * 64;

    // ---- staging ----
    hist[tid] = 0; hist[tid + 256] = 0;
    #pragma unroll
    for (int p = 0; p < 2; ++p) {
        int id = p * 256 + tid;
        int r = id >> 3, c = id & 7;
        *(float4*)&XT[r * 32 + c * 4] =
            *(const float4*)&X[(size_t)(b0 + r) * DX + c * 4];
    }
    #pragma unroll
    for (int p = 0; p < 16; ++p) {
        int id = p * 256 + tid;
        int r = id >> 3, c = id & 7;
        int cc = (c + (r >> 3)) & 7;       // rotation keyed by owner lane r>>3
        *(float4*)&CT[r * 32 + cc * 4] =
            *(const float4*)&C[(size_t)(seg * SEG + r) * DX + c * 4];
    }
    __syncthreads();

    if (tid < 64) {
        float s = 0.f;
        for (int k = 0; k < 32; ++k) { float v = XT[tid * 32 + k]; s += v * v; }
        xn[tid] = s;
    }
    #pragma unroll
    for (int pp = 0; pp < 2; ++pp) {
        int d = pp * 256 + tid;
        float s = 0.f;
        #pragma unroll
        for (int c = 0; c < 8; ++c) {      // true k order: c*4+kk ascending
            int cc = (c + (d >> 3)) & 7;
            #pragma unroll
            for (int kk = 0; kk < 4; ++kk) {
                float v = CT[d * 32 + cc * 4 + kk];
                s += v * v;
            }
        }
        cni[d] = make_float2(s, expf(-2.f * LS[seg * SEG + d]));
    }
    __syncthreads();

    const int lane = tid & 63;
    const int wv = tid >> 6;

    // hoist cni for this lane's 8 d's (row-independent)
    float cnx[8], cny[8];
    #pragma unroll
    for (int q = 0; q < 8; ++q) {
        float2 t2 = cni[lane * 8 + q];
        cnx[q] = t2.x; cny[q] = t2.y;
    }

    #pragma unroll 1
    for (int batch = 0; batch < 2; ++batch) {
        const int rb = wv * 16 + batch * 8;    // 8 rows this batch
        float acc[8][8];
        #pragma unroll
        for (int r = 0; r < 8; ++r)
            #pragma unroll
            for (int q = 0; q < 8; ++q) acc[r][q] = 0.f;

        #pragma unroll
        for (int c = 0; c < 8; ++c) {
            const int cc = (c + lane) & 7;     // == (c + (d>>3))&7 for d=lane*8+q
            float4 cv[8];
            #pragma unroll
            for (int q = 0; q < 8; ++q)
                cv[q] = *(const float4*)&CT[(lane * 8 + q) * 32 + cc * 4];
            #pragma unroll
            for (int r = 0; r < 8; ++r) {
                float4 xv = *(const float4*)&XT[(rb + r) * 32 + c * 4];  // broadcast
                #pragma unroll
                for (int q = 0; q < 8; ++q) {
                    acc[r][q] += xv.x * cv[q].x;   // k = 4c .. 4c+3, in order
                    acc[r][q] += xv.y * cv[q].y;
                    acc[r][q] += xv.z * cv[q].z;
                    acc[r][q] += xv.w * cv[q].w;
                }
            }
        }

        // ---- select per row (values straight from registers) ----
        #pragma unroll
        for (int r = 0; r < 8; ++r) {
            const int lr = rb + r;                       // local row 0..63
            const int row = (b0 + lr) * 4 + seg;         // global b*4+seg
            const float xb = xn[lr];
            float e[8];
            #pragma unroll
            for (int q = 0; q < 8; ++q)
                e[q] = fmaxf(xb + cnx[q] - 2.f * acc[r][q], 0.f) * cny[q];

            float m = e[0];
            #pragma unroll
            for (int q = 1; q < 8; ++q) m = fminf(m, e[q]);
            m = wave_min_f(m);

            int c0 = 0;
            #pragma unroll
            for (int q = 0; q < 8; ++q) c0 += (e[q] <= m + 9.0f) ? 1 : 0;
            c0 = wave_sum_i(c0);

            float Tp = 9.0f;
            if (c0 > CAP) {
                const float rungs[5] = {7.5f, 6.f, 4.5f, 3.f, 1.5f};
                Tp = 0.75f;
                for (int rI = 0; rI < 5; ++rI) {
                    int cc2 = 0;
                    #pragma unroll
                    for (int q = 0; q < 8; ++q) cc2 += (e[q] <= m + rungs[rI]) ? 1 : 0;
                    cc2 = wave_sum_i(cc2);
                    if (cc2 <= CAP) { Tp = rungs[rI]; break; }
                }
            }
            const float thr = m + Tp;

            int loc = 0;
            #pragma unroll
            for (int q = 0; q < 8; ++q) loc += (e[q] <= thr) ? 1 : 0;
            int incl = loc, t;
            t = __shfl_up(incl, 1);  if (lane >= 1)  incl += t;
            t = __shfl_up(incl, 2);  if (lane >= 2)  incl += t;
            t = __shfl_up(incl, 4);  if (lane >= 4)  incl += t;
            t = __shfl_up(incl, 8);  if (lane >= 8)  incl += t;
            t = __shfl_up(incl, 16); if (lane >= 16) incl += t;
            t = __shfl_up(incl, 32); if (lane >= 32) incl += t;
            const int excl = incl - loc;
            const int total = __shfl(incl, 63);

            const int base = row * CAP;
            int slot = excl;
            #pragma unroll
            for (int q = 0; q < 8; ++q) {
                bool pass = (e[q] <= thr);
                if (pass && slot < CAP) {
                    if (seg == 0) {
                        sdv[lr * CAP + slot] = lane * 8 + q;
                        svv[lr * CAP + slot] = expf(-e[q]);
                    } else {
                        IDX[base + slot] = lane * 8 + q;      // seg-local d
                        VAL[base + slot] = expf(-e[q]);
                        atomicAdd(&hist[lane * 8 + q], 1);    // LDS, block-local
                    }
                }
                if (pass) slot++;
            }
            if (lane == 0) {
                int ct = total < CAP ? total : CAP;
                CNT[row] = ct;
                rcnt[lr] = ct;
            }
        }
    }
    __syncthreads();

    // HIST2 slice writeout (block == exactly one [seg][chunk] slice; seg0
    // slice stays zero, matching the old fused memset semantics)
    HIST2[((size_t)seg * NCH + chunk) * SEG + tid] = hist[tid];
    HIST2[((size_t)seg * NCH + chunk) * SEG + tid + 256] = hist[tid + 256];

    // ---- fused R0 (seg 0 blocks): R0[b,i] = sum_t sv[t]*G0[sd[t],i] ----
    // Reduction tree replicated group-exactly: a[j] == original wave j's acc.
    if (seg == 0) {
        const int tg = lane >> 4, iq = lane & 15;
        #pragma unroll 1
        for (int rr = 0; rr < 16; ++rr) {
            const int lr = wv * 16 + rr;
            const int cnt0 = rcnt[lr];
            float4 a[4];
            #pragma unroll
            for (int j = 0; j < 4; ++j) a[j] = make_float4(0.f, 0.f, 0.f, 0.f);
            #pragma unroll
            for (int j = 0; j < 4; ++j) {
                for (int tt = j * 4 + tg; tt < cnt0; tt += 16) {
                    int dd = sdv[lr * CAP + tt];
                    float v = svv[lr * CAP + tt];
                    float4 g = *(const float4*)&G0[(size_t)dd * RK + iq * 4];
                    a[j].x += v * g.x; a[j].y += v * g.y;
                    a[j].z += v * g.z; a[j].w += v * g.w;
                }
            }
            #pragma unroll
            for (int j = 0; j < 4; ++j) {
                a[j].x += __shfl_xor(a[j].x, 16); a[j].y += __shfl_xor(a[j].y, 16);
                a[j].z += __shfl_xor(a[j].z, 16); a[j].w += __shfl_xor(a[j].w, 16);
                a[j].x += __shfl_xor(a[j].x, 32); a[j].y += __shfl_xor(a[j].y, 32);
                a[j].z += __shfl_xor(a[j].z, 32); a[j].w += __shfl_xor(a[j].w, 32);
            }
            if (tg == 0) {
                float4 s4;
                s4.x = (a[0].x + a[1].x) + (a[2].x + a[3].x);
                s4.y = (a[0].y + a[1].y) + (a[2].y + a[3].y);
                s4.z = (a[0].z + a[1].z) + (a[2].z + a[3].z);
                s4.w = (a[0].w + a[1].w) + (a[2].w + a[3].w);
                *(float4*)&R0v[(size_t)(b0 + lr) * RK + iq * 4] = s4;
            }
        }
    }
}

// ---------------------------------------------------------------------------
// g_split_dev<J>: pack G stage into per-d tiles GT[d] = [hi 8KB | lo 8KB]
// (J=32: 4KB|4KB), XOR-swizzle baked into GLOBAL layout so inv_stage can DMA
// the tile LINEARLY into LDS and read B-fragments conflict-free (rule #21).
// ---------------------------------------------------------------------------
template <int J>
static __device__ __forceinline__ void g_split_dev(
    const float* __restrict__ G, unsigned short* __restrict__ GT,
    int d, int tid, char* smem)
{
    float (*g)[J + 4] = (float (*)[J + 4])smem;      // [k][j], padded
    #pragma unroll
    for (int p = 0; p < J / 16; ++p) {               // 64*J/4 float4s / 256 thr
        int id = p * 256 + tid;
        int k = id / (J / 4), j0 = (id % (J / 4)) * 4;
        *(float4*)&g[k][j0] = *(const float4*)&G[((size_t)k * SEG + d) * J + j0];
    }
    __syncthreads();
    constexpr int TPJ = 256 / J;             // threads per j-row (4 or 8)
    constexpr int KPT = 64 / TPJ;            // k per thread (16 or 8)
    const int j = tid / TPJ, kc0 = (tid % TPJ) * (KPT / 8);
    unsigned short* tile = GT + (size_t)d * (2 * J * 64);
    #pragma unroll
    for (int vb = 0; vb < KPT / 8; ++vb) {
        int kchunk = kc0 + vb, k0 = kchunk * 8;
        us8 vh, vl;
        #pragma unroll
        for (int e = 0; e < 8; ++e) {
            float x = g[k0 + e][j];
            unsigned short h = f2bf(x);
            vh[e] = h;
            vl[e] = f2bf(x - bf2f(h));
        }
        int kcs = kchunk ^ (j & 7);
        *(us8*)&tile[j * 64 + kcs * 8]           = vh;
        *(us8*)&tile[J * 64 + j * 64 + kcs * 8]  = vl;
    }
}

// ---------------------------------------------------------------------------
// scan2 + G1-split fused: scan2 occupies only 4 CUs; the 512 split blocks
// fill the idle CUs for free.
// ---------------------------------------------------------------------------
__global__ __launch_bounds__(256) void scan2_split_kernel(
    const int* __restrict__ HIST2, int* __restrict__ OFFS,
    int* __restrict__ LEN, int* __restrict__ CHOFF,
    int* __restrict__ Q, int* __restrict__ QCNT,
    const float* __restrict__ G1, unsigned short* __restrict__ GT1)
{
    __shared__ alignas(16) char smem[64 * 68 * 4];   // 17.4 KB (split path)
    __shared__ int wsum[4], wsum2[4];

    if ((int)blockIdx.x >= 4) {
        g_split_dev<64>(G1, GT1, (int)blockIdx.x - 4, threadIdx.x, smem);
        return;
    }

    const int seg = blockIdx.x;
    const int tid = threadIdx.x;
    const int lane = tid & 63, wave = tid >> 6;
    const int d0 = tid * 2;

    int tot0 = 0, tot1 = 0;
    for (int c = 0; c < NCH; ++c) {
        int2 h = *(const int2*)&HIST2[(seg * NCH + c) * SEG + d0];
        tot0 += h.x; tot1 += h.y;
    }
    int s = tot0 + tot1;
    int incl = s, t;
    t = __shfl_up(incl, 1);  if (lane >= 1)  incl += t;
    t = __shfl_up(incl, 2);  if (lane >= 2)  incl += t;
    t = __shfl_up(incl, 4);  if (lane >= 4)  incl += t;
    t = __shfl_up(incl, 8);  if (lane >= 8)  incl += t;
    t = __shfl_up(incl, 16); if (lane >= 16) incl += t;
    t = __shfl_up(incl, 32); if (lane >= 32) incl += t;
    if (lane == 63) wsum[wave] = incl;
    const int nch0 = (tot0 + CHUNK - 1) / CHUNK, nch1 = (tot1 + CHUNK - 1) / CHUNK;
    int s2 = nch0 + nch1;
    int incl2 = s2;
    t = __shfl_up(incl2, 1);  if (lane >= 1)  incl2 += t;
    t = __shfl_up(incl2, 2);  if (lane >= 2)  incl2 += t;
    t = __shfl_up(incl2, 4);  if (lane >= 4)  incl2 += t;
    t = __shfl_up(incl2, 8);  if (lane >= 8)  incl2 += t;
    t = __shfl_up(incl2, 16); if (lane >= 16) incl2 += t;
    t = __shfl_up(incl2, 32); if (lane >= 32) incl2 += t;
    if (lane == 63) wsum2[wave] = incl2;
    __syncthreads();
    int woff = 0, woff2 = 0;
    #pragma unroll
    for (int w = 0; w < 4; ++w) if (w < wave) { woff += wsum[w]; woff2 += wsum2[w]; }
    const int excl  = woff + incl - s;
    const int excl2 = woff2 + incl2 - s2;

    OFFS[seg * SEG + d0] = excl;
    OFFS[seg * SEG + d0 + 1] = excl + tot0;
    LEN[seg * SEG + d0] = tot0;
    LEN[seg * SEG + d0 + 1] = tot1;

    int run0 = excl, run1 = excl + tot0;
    for (int c = 0; c < NCH; ++c) {
        int i0 = (seg * NCH + c) * SEG + d0;
        int2 h = *(const int2*)&HIST2[i0];
        *(int2*)&CHOFF[i0] = make_int2(run0, run1);
        run0 += h.x; run1 += h.y;
    }

    int qb = excl2;
    for (int c = 0; c < nch0; ++c) Q[seg * QMAX + qb + c] = (d0 << 16) | c;
    qb += nch0;
    for (int c = 0; c < nch1; ++c) Q[seg * QMAX + qb + c] = ((d0 + 1) << 16) | c;
    if (tid == 255) QCNT[seg] = woff2 + incl2;
}

// ---------------------------------------------------------------------------
// Scatter (LDS atomics only): block = (chunk of 64 b's, seg in 1..3).
// ---------------------------------------------------------------------------
__global__ __launch_bounds__(256) void scatter_kernel(
    const int* __restrict__ CNT, const int* __restrict__ IDX,
    const float* __restrict__ VAL, const int* __restrict__ CHOFF,
    int* __restrict__ BL, float* __restrict__ PV, int* __restrict__ FWD)
{
    __shared__ int cur[SEG];
    const int tid = threadIdx.x;
    const int chunk = blockIdx.x;
    const int seg = blockIdx.y + 1;
    cur[tid] = CHOFF[(seg * NCH + chunk) * SEG + tid];
    cur[tid + 256] = CHOFF[(seg * NCH + chunk) * SEG + tid + 256];
    __syncthreads();

    const int wave = tid >> 6, lane = tid & 63;
    #pragma unroll 4
    for (int i = 0; i < 16; ++i) {
        const int b = chunk * 64 + wave * 16 + i;
        const int cnt = CNT[b * 4 + seg];
        if (lane < cnt) {
            const int base = (b * 4 + seg) * CAP;
            int d = IDX[base + lane];
            float v = VAL[base + lane];
            int pos = atomicAdd(&cur[d], 1);          // LDS atomic
            BL[(size_t)(seg - 1) * NBCAP + pos] = b;
            PV[(size_t)(seg - 1) * NBCAP + pos] = v;
            FWD[(size_t)(seg - 1) * NBCAP + pos] = b * CAP + lane;
        }
    }
}

// ---------------------------------------------------------------------------
// Inverted stage via MFMA, staging-optimized (unchanged from round 2):
// GT tile DMA'd linearly (global_load_lds dwordx4), B-frag reads conflict-
// free under the baked XOR layout; 3-term bf16 split.
// ---------------------------------------------------------------------------
template <int NOUT>
__global__ __launch_bounds__(256) void inv_stage_mfma(
    const float* __restrict__ TIN, const unsigned short* __restrict__ GT,
    const int* __restrict__ Qs, const int* __restrict__ QCNTs,
    const int* __restrict__ LENs, const int* __restrict__ OFFSs,
    const int* __restrict__ BLs, const float* __restrict__ PVs,
    const int* __restrict__ FWDs, unsigned short* __restrict__ CONTRIB)
{
    constexpr int KP = 88;   // tin row pitch (shorts): 176B, ~2-way banks, 16B-aligned
    __shared__ alignas(16) unsigned short tinH[64 * KP];
    __shared__ alignas(16) unsigned short tinL[64 * KP];
    __shared__ alignas(16) unsigned short gHL[2 * NOUT * 64];  // [hi|lo], swizzled
    __shared__ float ph[64];
    __shared__ int   fw[64];

    if ((int)blockIdx.x >= QCNTs[0]) return;
    const int tid = threadIdx.x;
    const int lane = tid & 63;
    const int wv = tid >> 6;
    const int desc = Qs[blockIdx.x];
    const int d = desc >> 16, cidx = desc & 0xffff;
    const int len = LENs[d];
    const int off0 = OFFSs[d];
    const int ebase = cidx * CHUNK;

    // async GT tile DMA: NCHK x 1KB chunks, linear LDS dest (wave-uniform base)
    constexpr int NCHK = (2 * NOUT * 64 * 2) / 1024;   // 16 (J=64) or 8 (J=32)
    {
        const char* gsrc = (const char*)(GT + (size_t)d * (2 * NOUT * 64));
        #pragma unroll
        for (int i = 0; i < NCHK / 4; ++i) {
            int c = wv * (NCHK / 4) + i;
            async_copy16(gsrc + c * 1024 + lane * 16, (char*)gHL + c * 1024);
        }
    }
    // stage TIN rows (gather via BL), split hi/lo — overlaps the DMA
    #pragma unroll
    for (int p = 0; p < 4; ++p) {
        int f = p * 256 + tid;
        int en = f >> 4, c4 = (f & 15) * 4;
        int eidx = ebase + en;
        int brow = (eidx < len) ? BLs[off0 + eidx] : 0;
        float4 tv = *(const float4*)&TIN[(size_t)brow * RK + c4];
        ushort4 h, l;
        h.x = f2bf(tv.x); l.x = f2bf(tv.x - bf2f(h.x));
        h.y = f2bf(tv.y); l.y = f2bf(tv.y - bf2f(h.y));
        h.z = f2bf(tv.z); l.z = f2bf(tv.z - bf2f(h.z));
        h.w = f2bf(tv.w); l.w = f2bf(tv.w - bf2f(h.w));
        *(ushort4*)&tinH[en * KP + c4] = h;
        *(ushort4*)&tinL[en * KP + c4] = l;
    }
    if (tid < 64) {
        int ie = ebase + tid;
        bool ok = ie < len;
        ph[tid] = ok ? PVs[off0 + ie] : 0.f;
        fw[tid] = ok ? FWDs[off0 + ie] : 0;
    }
    __syncthreads();   // drains vmcnt -> DMA complete, LDS writes visible

    const int arow = ((wv << 4) | (lane & 15)) * KP;
    const int kg = (lane >> 4) << 3;              // 0,8,16,24 (shorts)
    const bfrag aH0 = *(const bfrag*)&tinH[arow + kg];
    const bfrag aH1 = *(const bfrag*)&tinH[arow + 32 + kg];
    const bfrag aL0 = *(const bfrag*)&tinL[arow + kg];
    const bfrag aL1 = *(const bfrag*)&tinL[arow + 32 + kg];

    const int col = lane & 15;
    const int kc = lane >> 4;                     // k-chunk 0..3 (low half)
    constexpr int NT = NOUT / 16;
    f32x4 acc[NT];
    #pragma unroll
    for (int jt = 0; jt < NT; ++jt) {
        acc[jt] = (f32x4)(0.0f);
        const int jb = jt * 16 + col;
        const int sw = jb & 7;
        const int rb = jb * 64;
        bfrag bH0 = *(const bfrag*)&gHL[rb + ((kc ^ sw) * 8)];
        bfrag bH1 = *(const bfrag*)&gHL[rb + (((kc + 4) ^ sw) * 8)];
        bfrag bL0 = *(const bfrag*)&gHL[NOUT * 64 + rb + ((kc ^ sw) * 8)];
        bfrag bL1 = *(const bfrag*)&gHL[NOUT * 64 + rb + (((kc + 4) ^ sw) * 8)];
        acc[jt] = __builtin_amdgcn_mfma_f32_16x16x32_bf16(aH0, bH0, acc[jt], 0, 0, 0);
        acc[jt] = __builtin_amdgcn_mfma_f32_16x16x32_bf16(aL0, bH0, acc[jt], 0, 0, 0);
        acc[jt] = __builtin_amdgcn_mfma_f32_16x16x32_bf16(aH0, bL0, acc[jt], 0, 0, 0);
        acc[jt] = __builtin_amdgcn_mfma_f32_16x16x32_bf16(aH1, bH1, acc[jt], 0, 0, 0);
        acc[jt] = __builtin_amdgcn_mfma_f32_16x16x32_bf16(aL1, bH1, acc[jt], 0, 0, 0);
        acc[jt] = __builtin_amdgcn_mfma_f32_16x16x32_bf16(aH1, bL1, acc[jt], 0, 0, 0);
    }

    __syncthreads();                 // all LDS reads done -> reuse tinH as sout
    unsigned short* sout = tinH;     // pitch KP (=88)
    {
        const int r0 = (wv << 4) | ((lane >> 4) << 2);   // C/D row base
        const float p0 = ph[r0 + 0], p1 = ph[r0 + 1];
        const float p2 = ph[r0 + 2], p3 = ph[r0 + 3];
        #pragma unroll
        for (int jt = 0; jt < NT; ++jt) {
            sout[(r0 + 0) * KP + jt * 16 + col] = f2bf(acc[jt][0] * p0);
            sout[(r0 + 1) * KP + jt * 16 + col] = f2bf(acc[jt][1] * p1);
            sout[(r0 + 2) * KP + jt * 16 + col] = f2bf(acc[jt][2] * p2);
            sout[(r0 + 3) * KP + jt * 16 + col] = f2bf(acc[jt][3] * p3);
        }
    }
    __syncthreads();

    // coalesced forward-order stores: 16B per thread-slot via FWD slots
    constexpr int VPT = NOUT / 32;               // us8 per thread (2 or 1)
    #pragma unroll
    for (int v = 0; v < VPT; ++v) {
        int id = v * 256 + tid;
        int en = id / (NOUT / 8);
        int jp = (id % (NOUT / 8)) * 8;
        if (ebase + en < len) {
            int dst = fw[en];
            us8 val = *(const us8*)&sout[en * KP + jp];
            *(us8*)&CONTRIB[(size_t)dst * NOUT + jp] = val;
        }
    }
}

// ---------------------------------------------------------------------------
// Gather (owner-writes, sequential bf16 reads, fp32 accumulate) — optionally
// fused with the NEXT stage's g_split (independent work, fills launch slack).
// ---------------------------------------------------------------------------
template <int NOUT, int JSPLIT>
__global__ __launch_bounds__(256) void gather_split_kernel(
    const int* __restrict__ CNT, const unsigned short* __restrict__ CONTRIB,
    float* __restrict__ TOUT, int seg,
    const float* __restrict__ Gn, unsigned short* __restrict__ GTn)
{
    __shared__ alignas(16) char smem[64 * 68 * 4];
    if ((int)blockIdx.x >= NB / 4) {
        g_split_dev<JSPLIT>(Gn, GTn, (int)blockIdx.x - NB / 4, threadIdx.x, smem);
        return;
    }
    constexpr int JL = NOUT / 4;
    constexpr int TG = 64 / JL;
    const int tid = threadIdx.x;
    const int b = blockIdx.x * 4 + (tid >> 6);
    const int lane = tid & 63;
    const int tg = lane / JL, iq = lane % JL;
    const int cnt = CNT[b * 4 + seg];
    const unsigned short* src = &CONTRIB[(size_t)b * CAP * NOUT];
    float4 acc = make_float4(0.f, 0.f, 0.f, 0.f);
    #pragma unroll 2
    for (int t = tg; t < cnt; t += TG) {
        ushort4 v = *(const ushort4*)&src[(size_t)t * NOUT + iq * 4];
        acc.x += bf2f(v.x); acc.y += bf2f(v.y);
        acc.z += bf2f(v.z); acc.w += bf2f(v.w);
    }
    #pragma unroll
    for (int off = JL; off < 64; off <<= 1) {
        acc.x += __shfl_xor(acc.x, off); acc.y += __shfl_xor(acc.y, off);
        acc.z += __shfl_xor(acc.z, off); acc.w += __shfl_xor(acc.w, off);
    }
    if (tg == 0) *(float4*)&TOUT[(size_t)b * NOUT + iq * 4] = acc;
}

template <int NOUT>
__global__ __launch_bounds__(256) void gather_kernel(
    const int* __restrict__ CNT, const unsigned short* __restrict__ CONTRIB,
    float* __restrict__ TOUT, int seg)
{
    constexpr int JL = NOUT / 4;
    constexpr int TG = 64 / JL;
    const int tid = threadIdx.x;
    const int b = blockIdx.x * 4 + (tid >> 6);
    const int lane = tid & 63;
    const int tg = lane / JL, iq = lane % JL;
    const int cnt = CNT[b * 4 + seg];
    const unsigned short* src = &CONTRIB[(size_t)b * CAP * NOUT];
    float4 acc = make_float4(0.f, 0.f, 0.f, 0.f);
    #pragma unroll 2
    for (int t = tg; t < cnt; t += TG) {
        ushort4 v = *(const ushort4*)&src[(size_t)t * NOUT + iq * 4];
        acc.x += bf2f(v.x); acc.y += bf2f(v.y);
        acc.z += bf2f(v.z); acc.w += bf2f(v.w);
    }
    #pragma unroll
    for (int off = JL; off < 64; off <<= 1) {
        acc.x += __shfl_xor(acc.x, off); acc.y += __shfl_xor(acc.y, off);
        acc.z += __shfl_xor(acc.z, off); acc.w += __shfl_xor(acc.w, off);
    }
    if (tg == 0) *(float4*)&TOUT[(size_t)b * NOUT + iq * 4] = acc;
}

// ---------------------------------------------------------------------------
extern "C" void kernel_launch(void* const* d_in, const int* in_sizes, int n_in,
                              void* d_out, int out_size, void* d_ws, size_t ws_size,
                              hipStream_t stream)
{
    const float* X  = (const float*)d_in[0];
    const float* C  = (const float*)d_in[1];
    const float* LS = (const float*)d_in[2];
    const float* G0 = (const float*)d_in[3];
    const float* G1 = (const float*)d_in[4];
    const float* G2 = (const float*)d_in[5];
    const float* G3 = (const float*)d_in[6];
    float* out = (float*)d_out;

    // CONTRIB (33.5 MB bf16) occupies the old E region (E itself is gone —
    // select_fused keeps it in registers). GT2 aliases IDX+VAL (dead after
    // scatter). GT1/GT3 live in an 8 MB arena at the end.
    char* ws = (char*)d_ws;
    unsigned short* CONTRIB = (unsigned short*)ws;
    size_t o = (size_t)NB * NCEN * 4;                               // 33.5 MB
    int*   CNT   = (int*)(ws + o);   o += (size_t)NB * 4 * 4;       // 64 KB
    int*   IDX   = (int*)(ws + o);   o += (size_t)NB * 4 * CAP * 4; // 4 MB
    float* VAL   = (float*)(ws + o); o += (size_t)NB * 4 * CAP * 4; // 4 MB
    int*   FWD   = (int*)(ws + o);   o += (size_t)3 * NBCAP * 4;    // 3 MB
    int*   HIST2 = (int*)(ws + o);   o += (size_t)4 * NCH * SEG * 4;// 512 KB
    int*   CHOFF = (int*)(ws + o);   o += (size_t)4 * NCH * SEG * 4;// 512 KB
    int*   OFFS  = (int*)(ws + o);   o += 4 * SEG * 4;              // 8 KB
    int*   LEN   = (int*)(ws + o);   o += 4 * SEG * 4;              // 8 KB
    int*   Q     = (int*)(ws + o);   o += (size_t)4 * QMAX * 4;     // 74 KB
    int*   QCNT  = (int*)(ws + o);   o += 64;
    int*   BL    = (int*)(ws + o);   o += (size_t)3 * NBCAP * 4;    // 3 MB
    float* PV    = (float*)(ws + o); o += (size_t)3 * NBCAP * 4;    // 3 MB
    float* R0v   = (float*)(ws + o); o += (size_t)NB * RK * 4;      // 1 MB
    float* t1    = (float*)(ws + o); o += (size_t)NB * RK * 4;      // 1 MB
    float* t2    = (float*)(ws + o); o += (size_t)NB * RK * 4;      // 1 MB
    unsigned short* GT1 = (unsigned short*)(ws + o);
    o += (size_t)SEG * 2 * 64 * 64 * 2;                             // 8 MB arena

    unsigned short* GT2 = (unsigned short*)IDX;   // 8 MB: IDX+VAL, dead post-scatter
    unsigned short* GT3 = GT1;                    // 4 MB: GT1 dead after inv1

    select_fused<<<dim3(NCH, 4), 256, 0, stream>>>(
        X, C, LS, G0, CNT, IDX, VAL, HIST2, R0v);
    scan2_split_kernel<<<4 + SEG, 256, 0, stream>>>(
        HIST2, OFFS, LEN, CHOFF, Q, QCNT, G1, GT1);
    scatter_kernel<<<dim3(NCH, 3), 256, 0, stream>>>(CNT, IDX, VAL, CHOFF, BL, PV, FWD);

    inv_stage_mfma<64><<<QMAX, 256, 0, stream>>>(
        R0v, GT1, Q + 1 * QMAX, QCNT + 1, LEN + SEG, OFFS + SEG,
        BL, PV, FWD, CONTRIB);
    gather_split_kernel<64, 64><<<NB / 4 + SEG, 256, 0, stream>>>(
        CNT, CONTRIB, t1, 1, G2, GT2);

    inv_stage_mfma<64><<<QMAX, 256, 0, stream>>>(
        t1, GT2, Q + 2 * QMAX, QCNT + 2, LEN + 2 * SEG, OFFS + 2 * SEG,
        BL + (size_t)NBCAP, PV + (size_t)NBCAP, FWD + (size_t)NBCAP, CONTRIB);
    gather_split_kernel<64, 32><<<NB / 4 + SEG, 256, 0, stream>>>(
        CNT, CONTRIB, t2, 2, G3, GT3);

    inv_stage_mfma<32><<<QMAX, 256, 0, stream>>>(
        t2, GT3, Q + 3 * QMAX, QCNT + 3, LEN + 3 * SEG, OFFS + 3 * SEG,
        BL + (size_t)2 * NBCAP, PV + (size_t)2 * NBCAP, FWD + (size_t)2 * NBCAP, CONTRIB);
    gather_kernel<32><<<NB / 4, 256, 0, stream>>>(CNT, CONTRIB, out, 3);
}

// Round 4
// 163.510 us; speedup vs baseline: 1.3565x; 1.3565x over previous
//
#include <hip/hip_runtime.h>
#include <math.h>

// Problem constants
#define NB    4096   // batch
#define NCEN  2048   // centres
#define DX    32     // feature dim
#define SEG   512    // centres per segment
#define RK    64     // TT rank
#define CAP   64     // max kept centres per (b, segment)
#define NBCAP (NB * CAP)
#define NCH   64     // b-chunks of 64 rows each (two-level scatter scan)
#define CHUNK 64     // entries per inv_stage work item
#define QMAX  (NBCAP / CHUNK + SEG)   // 4608 max chunks per segment

typedef unsigned short us8 __attribute__((ext_vector_type(8)));
typedef short bfrag __attribute__((ext_vector_type(8)));
typedef float f32x4 __attribute__((ext_vector_type(4)));

static __device__ __forceinline__ int wave_sum_i(int v) {
    v += __shfl_xor(v, 1);  v += __shfl_xor(v, 2);  v += __shfl_xor(v, 4);
    v += __shfl_xor(v, 8);  v += __shfl_xor(v, 16); v += __shfl_xor(v, 32);
    return v;
}
static __device__ __forceinline__ float wave_min_f(float v) {
    v = fminf(v, __shfl_xor(v, 1));  v = fminf(v, __shfl_xor(v, 2));
    v = fminf(v, __shfl_xor(v, 4));  v = fminf(v, __shfl_xor(v, 8));
    v = fminf(v, __shfl_xor(v, 16)); v = fminf(v, __shfl_xor(v, 32));
    return v;
}
// bf16 pack/unpack (RNE — truncation would bias coherently, RNE stays
// incoherent across terms). bf16 keeps fp32 exponent range.
static __device__ __forceinline__ unsigned short f2bf(float f) {
    unsigned u = __float_as_uint(f);
    u += 0x7FFFu + ((u >> 16) & 1u);
    return (unsigned short)(u >> 16);
}
static __device__ __forceinline__ float bf2f(unsigned short h) {
    return __uint_as_float(((unsigned)h) << 16);
}
// async global->LDS DMA, 16B per lane. LDS dest is wave-uniform base;
// global src is per-lane (guide §5, m97/m03).
static __device__ __forceinline__ void async_copy16(const void* g, void* l) {
    __builtin_amdgcn_global_load_lds(
        (const __attribute__((address_space(1))) unsigned int*)g,
        (__attribute__((address_space(3))) unsigned int*)l, 16, 0, 0);
}

// ---------------------------------------------------------------------------
// Pass A: E[b,d] = max(||x||^2+||c||^2-2 x.c, 0) * exp(-2 ls_d)
// blockIdx.y==0 blocks also zero HIST2 (fused memset).
// (R3 lesson: fusing this with rowselect costs occupancy (256 VGPR, 110 KB
// LDS, 1 block/CU) and loses 50 µs — keep the E round-trip, it's only ~11 µs.)
// ---------------------------------------------------------------------------
__global__ __launch_bounds__(256) void e_gemm(
    const float* __restrict__ X, const float* __restrict__ C,
    const float* __restrict__ LS, float* __restrict__ E, int* __restrict__ HIST2)
{
    __shared__ float XT[32 * 68];    // [k][b], stride 68
    __shared__ float CT[32 * 68];    // [k][d]
    __shared__ float xn[64];
    __shared__ float2 cni[64];       // (||c||^2, exp(-2 ls))

    const int tid = threadIdx.x;
    const int d0 = blockIdx.x * 64, b0 = blockIdx.y * 64;

    if (blockIdx.y == 0) {
        #pragma unroll
        for (int p = 0; p < 16; ++p)
            HIST2[blockIdx.x * 4096 + p * 256 + tid] = 0;
    }

    #pragma unroll
    for (int p = 0; p < 2; ++p) {
        int f = p * 256 + tid;               // 0..511
        int r = f >> 3, c4 = (f & 7) * 4;
        float4 xv = *(const float4*)&X[(size_t)(b0 + r) * DX + c4];
        XT[(c4 + 0) * 68 + r] = xv.x; XT[(c4 + 1) * 68 + r] = xv.y;
        XT[(c4 + 2) * 68 + r] = xv.z; XT[(c4 + 3) * 68 + r] = xv.w;
        float4 cv = *(const float4*)&C[(size_t)(d0 + r) * DX + c4];
        CT[(c4 + 0) * 68 + r] = cv.x; CT[(c4 + 1) * 68 + r] = cv.y;
        CT[(c4 + 2) * 68 + r] = cv.z; CT[(c4 + 3) * 68 + r] = cv.w;
    }
    __syncthreads();

    if (tid < 64) {
        float s = 0.f;
        for (int k = 0; k < 32; ++k) { float v = XT[k * 68 + tid]; s += v * v; }
        xn[tid] = s;
    } else if (tid < 128) {
        int d = tid - 64;
        float s = 0.f;
        for (int k = 0; k < 32; ++k) { float v = CT[k * 68 + d]; s += v * v; }
        cni[d] = make_float2(s, expf(-2.f * LS[d0 + d]));
    }
    __syncthreads();

    const int ty = tid >> 4, tx = tid & 15;
    float acc[4][4] = {};
    #pragma unroll 8
    for (int k = 0; k < 32; ++k) {
        float4 xv = *(const float4*)&XT[k * 68 + ty * 4];
        float4 cv = *(const float4*)&CT[k * 68 + tx * 4];
        acc[0][0] += xv.x * cv.x; acc[0][1] += xv.x * cv.y;
        acc[0][2] += xv.x * cv.z; acc[0][3] += xv.x * cv.w;
        acc[1][0] += xv.y * cv.x; acc[1][1] += xv.y * cv.y;
        acc[1][2] += xv.y * cv.z; acc[1][3] += xv.y * cv.w;
        acc[2][0] += xv.z * cv.x; acc[2][1] += xv.z * cv.y;
        acc[2][2] += xv.z * cv.z; acc[2][3] += xv.z * cv.w;
        acc[3][0] += xv.w * cv.x; acc[3][1] += xv.w * cv.y;
        acc[3][2] += xv.w * cv.z; acc[3][3] += xv.w * cv.w;
    }

    float2 c0v = cni[tx * 4 + 0], c1v = cni[tx * 4 + 1];
    float2 c2v = cni[tx * 4 + 2], c3v = cni[tx * 4 + 3];
    #pragma unroll
    for (int i = 0; i < 4; ++i) {
        float xb = xn[ty * 4 + i];
        float4 ev;
        ev.x = fmaxf(xb + c0v.x - 2.f * acc[i][0], 0.f) * c0v.y;
        ev.y = fmaxf(xb + c1v.x - 2.f * acc[i][1], 0.f) * c1v.y;
        ev.z = fmaxf(xb + c2v.x - 2.f * acc[i][2], 0.f) * c2v.y;
        ev.w = fmaxf(xb + c3v.x - 2.f * acc[i][3], 0.f) * c3v.y;
        *(float4*)&E[(size_t)(b0 + ty * 4 + i) * NCEN + d0 + tx * 4] = ev;
    }
}

// ---------------------------------------------------------------------------
// Pass B: per (b,seg) row: min, ladder threshold (T0=9.0), compact.
// Block = one b (4 waves = 4 segs); wave 0's list stays in LDS for fused R0.
// T-knob is SPENT (see history in prior rounds).
// ---------------------------------------------------------------------------
__global__ __launch_bounds__(256) void rowselect(
    const float* __restrict__ E, const float* __restrict__ G0,
    int* __restrict__ CNT, int* __restrict__ IDX, float* __restrict__ VAL,
    int* __restrict__ HIST2, float* __restrict__ R0v)
{
    __shared__ int   sd[CAP];
    __shared__ float sv[CAP];
    __shared__ int   scnt;
    __shared__ float4 red[4][16];

    const int tid = threadIdx.x;
    const int lane = tid & 63;
    const int row = blockIdx.x * 4 + (tid >> 6);   // row = b*4 + seg
    const int b = blockIdx.x, seg = row & 3;       // seg == wave index
    const float* er = &E[(size_t)b * NCEN + seg * SEG];

    float4 ea = *(const float4*)&er[lane * 8];
    float4 eb = *(const float4*)&er[lane * 8 + 4];
    float e[8] = {ea.x, ea.y, ea.z, ea.w, eb.x, eb.y, eb.z, eb.w};

    float m = e[0];
    #pragma unroll
    for (int q = 1; q < 8; ++q) m = fminf(m, e[q]);
    m = wave_min_f(m);

    int c0 = 0;
    #pragma unroll
    for (int q = 0; q < 8; ++q) c0 += (e[q] <= m + 9.0f) ? 1 : 0;
    c0 = wave_sum_i(c0);

    float Tp = 9.0f;
    if (c0 > CAP) {
        const float rungs[5] = {7.5f, 6.f, 4.5f, 3.f, 1.5f};
        Tp = 0.75f;
        for (int rI = 0; rI < 5; ++rI) {
            int cc = 0;
            #pragma unroll
            for (int q = 0; q < 8; ++q) cc += (e[q] <= m + rungs[rI]) ? 1 : 0;
            cc = wave_sum_i(cc);
            if (cc <= CAP) { Tp = rungs[rI]; break; }
        }
    }
    const float thr = m + Tp;

    int loc = 0;
    #pragma unroll
    for (int q = 0; q < 8; ++q) loc += (e[q] <= thr) ? 1 : 0;
    int incl = loc, t;
    t = __shfl_up(incl, 1);  if (lane >= 1)  incl += t;
    t = __shfl_up(incl, 2);  if (lane >= 2)  incl += t;
    t = __shfl_up(incl, 4);  if (lane >= 4)  incl += t;
    t = __shfl_up(incl, 8);  if (lane >= 8)  incl += t;
    t = __shfl_up(incl, 16); if (lane >= 16) incl += t;
    t = __shfl_up(incl, 32); if (lane >= 32) incl += t;
    const int excl = incl - loc;
    const int total = __shfl(incl, 63);

    const int base = row * CAP;
    int* h2 = &HIST2[(seg * NCH + (b >> 6)) * SEG];
    int slot = excl;
    #pragma unroll
    for (int q = 0; q < 8; ++q) {
        bool pass = (e[q] <= thr);
        if (pass && slot < CAP) {
            if (seg == 0) {
                sd[slot] = lane * 8 + q;
                sv[slot] = expf(-e[q]);
            } else {
                IDX[base + slot] = lane * 8 + q;      // seg-local d
                VAL[base + slot] = expf(-e[q]);
                atomicAdd(&h2[lane * 8 + q], 1);      // fire-and-forget
            }
        }
        if (pass) slot++;
    }
    if (lane == 0) CNT[row] = total < CAP ? total : CAP;
    if (seg == 0 && lane == 0) scnt = total < CAP ? total : CAP;
    __syncthreads();

    // Fused R0[b,i] = sum_t sv[t] * G0[sd[t], i]
    const int wv = tid >> 6;
    const int tg = lane >> 4, iq = lane & 15;
    const int cnt0 = scnt;
    float4 acc = make_float4(0.f, 0.f, 0.f, 0.f);
    for (int tt = wv * 4 + tg; tt < cnt0; tt += 16) {
        int d = sd[tt];
        float v = sv[tt];
        float4 g = *(const float4*)&G0[(size_t)d * RK + iq * 4];
        acc.x += v * g.x; acc.y += v * g.y; acc.z += v * g.z; acc.w += v * g.w;
    }
    acc.x += __shfl_xor(acc.x, 16); acc.y += __shfl_xor(acc.y, 16);
    acc.z += __shfl_xor(acc.z, 16); acc.w += __shfl_xor(acc.w, 16);
    acc.x += __shfl_xor(acc.x, 32); acc.y += __shfl_xor(acc.y, 32);
    acc.z += __shfl_xor(acc.z, 32); acc.w += __shfl_xor(acc.w, 32);
    if (lane < 16) red[wv][iq] = acc;
    __syncthreads();
    if (tid < 16) {
        float4 a0 = red[0][tid], a1 = red[1][tid];
        float4 a2 = red[2][tid], a3 = red[3][tid];
        float4 s4;
        s4.x = (a0.x + a1.x) + (a2.x + a3.x);
        s4.y = (a0.y + a1.y) + (a2.y + a3.y);
        s4.z = (a0.z + a1.z) + (a2.z + a3.z);
        s4.w = (a0.w + a1.w) + (a2.w + a3.w);
        *(float4*)&R0v[(size_t)b * RK + tid * 4] = s4;
    }
}

// ---------------------------------------------------------------------------
// g_split_dev<J>: pack G stage into per-d tiles GT[d] = [hi 8KB | lo 8KB]
// (J=32: 4KB|4KB), XOR-swizzle baked into GLOBAL layout so inv_stage can DMA
// the tile LINEARLY into LDS and read B-fragments conflict-free (rule #21).
// ---------------------------------------------------------------------------
template <int J>
static __device__ __forceinline__ void g_split_dev(
    const float* __restrict__ G, unsigned short* __restrict__ GT,
    int d, int tid, char* smem)
{
    float (*g)[J + 4] = (float (*)[J + 4])smem;      // [k][j], padded
    #pragma unroll
    for (int p = 0; p < J / 16; ++p) {               // 64*J/4 float4s / 256 thr
        int id = p * 256 + tid;
        int k = id / (J / 4), j0 = (id % (J / 4)) * 4;
        *(float4*)&g[k][j0] = *(const float4*)&G[((size_t)k * SEG + d) * J + j0];
    }
    __syncthreads();
    constexpr int TPJ = 256 / J;             // threads per j-row (4 or 8)
    constexpr int KPT = 64 / TPJ;            // k per thread (16 or 8)
    const int j = tid / TPJ, kc0 = (tid % TPJ) * (KPT / 8);
    unsigned short* tile = GT + (size_t)d * (2 * J * 64);
    #pragma unroll
    for (int vb = 0; vb < KPT / 8; ++vb) {
        int kchunk = kc0 + vb, k0 = kchunk * 8;
        us8 vh, vl;
        #pragma unroll
        for (int e = 0; e < 8; ++e) {
            float x = g[k0 + e][j];
            unsigned short h = f2bf(x);
            vh[e] = h;
            vl[e] = f2bf(x - bf2f(h));
        }
        int kcs = kchunk ^ (j & 7);
        *(us8*)&tile[j * 64 + kcs * 8]           = vh;
        *(us8*)&tile[J * 64 + j * 64 + kcs * 8]  = vl;
    }
}

// ---------------------------------------------------------------------------
// scan2 + G1-split fused: scan2 occupies only 4 CUs; the 512 split blocks
// fill the idle CUs for free.
// ---------------------------------------------------------------------------
__global__ __launch_bounds__(256) void scan2_split_kernel(
    const int* __restrict__ HIST2, int* __restrict__ OFFS,
    int* __restrict__ LEN, int* __restrict__ CHOFF,
    int* __restrict__ Q, int* __restrict__ QCNT,
    const float* __restrict__ G1, unsigned short* __restrict__ GT1)
{
    __shared__ alignas(16) char smem[64 * 68 * 4];   // 17.4 KB (split path)
    __shared__ int wsum[4], wsum2[4];

    if ((int)blockIdx.x >= 4) {
        g_split_dev<64>(G1, GT1, (int)blockIdx.x - 4, threadIdx.x, smem);
        return;
    }

    const int seg = blockIdx.x;
    const int tid = threadIdx.x;
    const int lane = tid & 63, wave = tid >> 6;
    const int d0 = tid * 2;

    int tot0 = 0, tot1 = 0;
    for (int c = 0; c < NCH; ++c) {
        int2 h = *(const int2*)&HIST2[(seg * NCH + c) * SEG + d0];
        tot0 += h.x; tot1 += h.y;
    }
    int s = tot0 + tot1;
    int incl = s, t;
    t = __shfl_up(incl, 1);  if (lane >= 1)  incl += t;
    t = __shfl_up(incl, 2);  if (lane >= 2)  incl += t;
    t = __shfl_up(incl, 4);  if (lane >= 4)  incl += t;
    t = __shfl_up(incl, 8);  if (lane >= 8)  incl += t;
    t = __shfl_up(incl, 16); if (lane >= 16) incl += t;
    t = __shfl_up(incl, 32); if (lane >= 32) incl += t;
    if (lane == 63) wsum[wave] = incl;
    const int nch0 = (tot0 + CHUNK - 1) / CHUNK, nch1 = (tot1 + CHUNK - 1) / CHUNK;
    int s2 = nch0 + nch1;
    int incl2 = s2;
    t = __shfl_up(incl2, 1);  if (lane >= 1)  incl2 += t;
    t = __shfl_up(incl2, 2);  if (lane >= 2)  incl2 += t;
    t = __shfl_up(incl2, 4);  if (lane >= 4)  incl2 += t;
    t = __shfl_up(incl2, 8);  if (lane >= 8)  incl2 += t;
    t = __shfl_up(incl2, 16); if (lane >= 16) incl2 += t;
    t = __shfl_up(incl2, 32); if (lane >= 32) incl2 += t;
    if (lane == 63) wsum2[wave] = incl2;
    __syncthreads();
    int woff = 0, woff2 = 0;
    #pragma unroll
    for (int w = 0; w < 4; ++w) if (w < wave) { woff += wsum[w]; woff2 += wsum2[w]; }
    const int excl  = woff + incl - s;
    const int excl2 = woff2 + incl2 - s2;

    OFFS[seg * SEG + d0] = excl;
    OFFS[seg * SEG + d0 + 1] = excl + tot0;
    LEN[seg * SEG + d0] = tot0;
    LEN[seg * SEG + d0 + 1] = tot1;

    int run0 = excl, run1 = excl + tot0;
    for (int c = 0; c < NCH; ++c) {
        int i0 = (seg * NCH + c) * SEG + d0;
        int2 h = *(const int2*)&HIST2[i0];
        *(int2*)&CHOFF[i0] = make_int2(run0, run1);
        run0 += h.x; run1 += h.y;
    }

    int qb = excl2;
    for (int c = 0; c < nch0; ++c) Q[seg * QMAX + qb + c] = (d0 << 16) | c;
    qb += nch0;
    for (int c = 0; c < nch1; ++c) Q[seg * QMAX + qb + c] = ((d0 + 1) << 16) | c;
    if (tid == 255) QCNT[seg] = woff2 + incl2;
}

// ---------------------------------------------------------------------------
// Scatter (LDS atomics only): block = (chunk of 64 b's, seg in 1..3).
// ---------------------------------------------------------------------------
__global__ __launch_bounds__(256) void scatter_kernel(
    const int* __restrict__ CNT, const int* __restrict__ IDX,
    const float* __restrict__ VAL, const int* __restrict__ CHOFF,
    int* __restrict__ BL, float* __restrict__ PV, int* __restrict__ FWD)
{
    __shared__ int cur[SEG];
    const int tid = threadIdx.x;
    const int chunk = blockIdx.x;
    const int seg = blockIdx.y + 1;
    cur[tid] = CHOFF[(seg * NCH + chunk) * SEG + tid];
    cur[tid + 256] = CHOFF[(seg * NCH + chunk) * SEG + tid + 256];
    __syncthreads();

    const int wave = tid >> 6, lane = tid & 63;
    #pragma unroll 4
    for (int i = 0; i < 16; ++i) {
        const int b = chunk * 64 + wave * 16 + i;
        const int cnt = CNT[b * 4 + seg];
        if (lane < cnt) {
            const int base = (b * 4 + seg) * CAP;
            int d = IDX[base + lane];
            float v = VAL[base + lane];
            int pos = atomicAdd(&cur[d], 1);          // LDS atomic
            BL[(size_t)(seg - 1) * NBCAP + pos] = b;
            PV[(size_t)(seg - 1) * NBCAP + pos] = v;
            FWD[(size_t)(seg - 1) * NBCAP + pos] = b * CAP + lane;
        }
    }
}

// ---------------------------------------------------------------------------
// Inverted stage via MFMA, occupancy-optimized (R4):
//  - NO tin LDS staging: each lane loads its A-fragment (16 contiguous fp32
//    of one L2-hot TIN row) directly from global and does the IDENTICAL
//    f2bf hi/lo split in registers -> bit-identical MFMA inputs.
//  - GT tile DMA'd linearly (global_load_lds); B-frag reads conflict-free
//    under the baked XOR layout.
//  - sout epilogue buffer ALIASES gHL (dead after last MFMA read).
//  LDS 38.8 KB -> 16.4 KB: 4 -> 8 blocks/CU.
// C/D map (HW-verified): col=lane&15, row=(lane>>4)*4+reg.
// ---------------------------------------------------------------------------
template <int NOUT>
__global__ __launch_bounds__(256) void inv_stage_mfma(
    const float* __restrict__ TIN, const unsigned short* __restrict__ GT,
    const int* __restrict__ Qs, const int* __restrict__ QCNTs,
    const int* __restrict__ LENs, const int* __restrict__ OFFSs,
    const int* __restrict__ BLs, const float* __restrict__ PVs,
    const int* __restrict__ FWDs, unsigned short* __restrict__ CONTRIB)
{
    constexpr int SP = NOUT + 8;     // sout pitch (shorts); fits inside gHL
    __shared__ alignas(16) unsigned short gHL[2 * NOUT * 64];  // [hi|lo], swizzled
    __shared__ float ph[64];
    __shared__ int   fw[64];
    static_assert(64 * SP <= 2 * NOUT * 64, "sout must fit in gHL");

    if ((int)blockIdx.x >= QCNTs[0]) return;
    const int tid = threadIdx.x;
    const int lane = tid & 63;
    const int wv = tid >> 6;
    const int desc = Qs[blockIdx.x];
    const int d = desc >> 16, cidx = desc & 0xffff;
    const int len = LENs[d];
    const int off0 = OFFSs[d];
    const int ebase = cidx * CHUNK;

    // async GT tile DMA: NCHK x 1KB chunks, linear LDS dest (wave-uniform base)
    constexpr int NCHK = (2 * NOUT * 64 * 2) / 1024;   // 16 (J=64) or 8 (J=32)
    {
        const char* gsrc = (const char*)(GT + (size_t)d * (2 * NOUT * 64));
        #pragma unroll
        for (int i = 0; i < NCHK / 4; ++i) {
            int c = wv * (NCHK / 4) + i;
            async_copy16(gsrc + c * 1024 + lane * 16, (char*)gHL + c * 1024);
        }
    }

    // A-fragments straight from global (L2-hot TIN, 1 MB): lane owns entry
    // row wv*16+(lane&15), k-chunks kg..kg+7 and 32+kg..32+kg+7. Identical
    // f2bf splits as the old staged path -> bit-identical fragments.
    const int myrow = ebase + wv * 16 + (lane & 15);
    const int brow = (myrow < len) ? BLs[off0 + myrow] : 0;
    const int kg = (lane >> 4) << 3;              // 0,8,16,24
    const float* tr = &TIN[(size_t)brow * RK];
    float4 u0 = *(const float4*)&tr[kg];
    float4 u1 = *(const float4*)&tr[kg + 4];
    float4 u2 = *(const float4*)&tr[32 + kg];
    float4 u3 = *(const float4*)&tr[32 + kg + 4];
    float av0[8] = {u0.x, u0.y, u0.z, u0.w, u1.x, u1.y, u1.z, u1.w};
    float av1[8] = {u2.x, u2.y, u2.z, u2.w, u3.x, u3.y, u3.z, u3.w};
    bfrag aH0, aH1, aL0, aL1;
    #pragma unroll
    for (int e = 0; e < 8; ++e) {
        unsigned short h0 = f2bf(av0[e]);
        aH0[e] = (short)h0; aL0[e] = (short)f2bf(av0[e] - bf2f(h0));
        unsigned short h1 = f2bf(av1[e]);
        aH1[e] = (short)h1; aL1[e] = (short)f2bf(av1[e] - bf2f(h1));
    }

    if (tid < 64) {
        int ie = ebase + tid;
        bool ok = ie < len;
        ph[tid] = ok ? PVs[off0 + ie] : 0.f;
        fw[tid] = ok ? FWDs[off0 + ie] : 0;
    }
    __syncthreads();   // drains vmcnt -> GT DMA complete, LDS writes visible

    const int col = lane & 15;
    const int kc = lane >> 4;                     // k-chunk 0..3 (low half)
    constexpr int NT = NOUT / 16;
    f32x4 acc[NT];
    #pragma unroll
    for (int jt = 0; jt < NT; ++jt) {
        acc[jt] = (f32x4)(0.0f);
        const int jb = jt * 16 + col;
        const int sw = jb & 7;
        const int rb = jb * 64;
        bfrag bH0 = *(const bfrag*)&gHL[rb + ((kc ^ sw) * 8)];
        bfrag bH1 = *(const bfrag*)&gHL[rb + (((kc + 4) ^ sw) * 8)];
        bfrag bL0 = *(const bfrag*)&gHL[NOUT * 64 + rb + ((kc ^ sw) * 8)];
        bfrag bL1 = *(const bfrag*)&gHL[NOUT * 64 + rb + (((kc + 4) ^ sw) * 8)];
        acc[jt] = __builtin_amdgcn_mfma_f32_16x16x32_bf16(aH0, bH0, acc[jt], 0, 0, 0);
        acc[jt] = __builtin_amdgcn_mfma_f32_16x16x32_bf16(aL0, bH0, acc[jt], 0, 0, 0);
        acc[jt] = __builtin_amdgcn_mfma_f32_16x16x32_bf16(aH0, bL0, acc[jt], 0, 0, 0);
        acc[jt] = __builtin_amdgcn_mfma_f32_16x16x32_bf16(aH1, bH1, acc[jt], 0, 0, 0);
        acc[jt] = __builtin_amdgcn_mfma_f32_16x16x32_bf16(aL1, bH1, acc[jt], 0, 0, 0);
        acc[jt] = __builtin_amdgcn_mfma_f32_16x16x32_bf16(aH1, bL1, acc[jt], 0, 0, 0);
    }

    __syncthreads();                 // all gHL reads done -> reuse as sout
    unsigned short* sout = gHL;      // pitch SP
    {
        const int r0 = (wv << 4) | ((lane >> 4) << 2);   // C/D row base
        const float p0 = ph[r0 + 0], p1 = ph[r0 + 1];
        const float p2 = ph[r0 + 2], p3 = ph[r0 + 3];
        #pragma unroll
        for (int jt = 0; jt < NT; ++jt) {
            sout[(r0 + 0) * SP + jt * 16 + col] = f2bf(acc[jt][0] * p0);
            sout[(r0 + 1) * SP + jt * 16 + col] = f2bf(acc[jt][1] * p1);
            sout[(r0 + 2) * SP + jt * 16 + col] = f2bf(acc[jt][2] * p2);
            sout[(r0 + 3) * SP + jt * 16 + col] = f2bf(acc[jt][3] * p3);
        }
    }
    __syncthreads();

    // coalesced forward-order stores: 16B per thread-slot via FWD slots
    constexpr int VPT = NOUT / 32;               // us8 per thread (2 or 1)
    #pragma unroll
    for (int v = 0; v < VPT; ++v) {
        int id = v * 256 + tid;
        int en = id / (NOUT / 8);
        int jp = (id % (NOUT / 8)) * 8;
        if (ebase + en < len) {
            int dst = fw[en];
            us8 val = *(const us8*)&sout[en * SP + jp];
            *(us8*)&CONTRIB[(size_t)dst * NOUT + jp] = val;
        }
    }
}

// ---------------------------------------------------------------------------
// Gather (owner-writes, sequential bf16 reads, fp32 accumulate) — optionally
// fused with the NEXT stage's g_split (independent work, fills launch slack).
// ---------------------------------------------------------------------------
template <int NOUT, int JSPLIT>
__global__ __launch_bounds__(256) void gather_split_kernel(
    const int* __restrict__ CNT, const unsigned short* __restrict__ CONTRIB,
    float* __restrict__ TOUT, int seg,
    const float* __restrict__ Gn, unsigned short* __restrict__ GTn)
{
    __shared__ alignas(16) char smem[64 * 68 * 4];
    if ((int)blockIdx.x >= NB / 4) {
        g_split_dev<JSPLIT>(Gn, GTn, (int)blockIdx.x - NB / 4, threadIdx.x, smem);
        return;
    }
    constexpr int JL = NOUT / 4;
    constexpr int TG = 64 / JL;
    const int tid = threadIdx.x;
    const int b = blockIdx.x * 4 + (tid >> 6);
    const int lane = tid & 63;
    const int tg = lane / JL, iq = lane % JL;
    const int cnt = CNT[b * 4 + seg];
    const unsigned short* src = &CONTRIB[(size_t)b * CAP * NOUT];
    float4 acc = make_float4(0.f, 0.f, 0.f, 0.f);
    #pragma unroll 2
    for (int t = tg; t < cnt; t += TG) {
        ushort4 v = *(const ushort4*)&src[(size_t)t * NOUT + iq * 4];
        acc.x += bf2f(v.x); acc.y += bf2f(v.y);
        acc.z += bf2f(v.z); acc.w += bf2f(v.w);
    }
    #pragma unroll
    for (int off = JL; off < 64; off <<= 1) {
        acc.x += __shfl_xor(acc.x, off); acc.y += __shfl_xor(acc.y, off);
        acc.z += __shfl_xor(acc.z, off); acc.w += __shfl_xor(acc.w, off);
    }
    if (tg == 0) *(float4*)&TOUT[(size_t)b * NOUT + iq * 4] = acc;
}

template <int NOUT>
__global__ __launch_bounds__(256) void gather_kernel(
    const int* __restrict__ CNT, const unsigned short* __restrict__ CONTRIB,
    float* __restrict__ TOUT, int seg)
{
    constexpr int JL = NOUT / 4;
    constexpr int TG = 64 / JL;
    const int tid = threadIdx.x;
    const int b = blockIdx.x * 4 + (tid >> 6);
    const int lane = tid & 63;
    const int tg = lane / JL, iq = lane % JL;
    const int cnt = CNT[b * 4 + seg];
    const unsigned short* src = &CONTRIB[(size_t)b * CAP * NOUT];
    float4 acc = make_float4(0.f, 0.f, 0.f, 0.f);
    #pragma unroll 2
    for (int t = tg; t < cnt; t += TG) {
        ushort4 v = *(const ushort4*)&src[(size_t)t * NOUT + iq * 4];
        acc.x += bf2f(v.x); acc.y += bf2f(v.y);
        acc.z += bf2f(v.z); acc.w += bf2f(v.w);
    }
    #pragma unroll
    for (int off = JL; off < 64; off <<= 1) {
        acc.x += __shfl_xor(acc.x, off); acc.y += __shfl_xor(acc.y, off);
        acc.z += __shfl_xor(acc.z, off); acc.w += __shfl_xor(acc.w, off);
    }
    if (tg == 0) *(float4*)&TOUT[(size_t)b * NOUT + iq * 4] = acc;
}

// ---------------------------------------------------------------------------
extern "C" void kernel_launch(void* const* d_in, const int* in_sizes, int n_in,
                              void* d_out, int out_size, void* d_ws, size_t ws_size,
                              hipStream_t stream)
{
    const float* X  = (const float*)d_in[0];
    const float* C  = (const float*)d_in[1];
    const float* LS = (const float*)d_in[2];
    const float* G0 = (const float*)d_in[3];
    const float* G1 = (const float*)d_in[4];
    const float* G2 = (const float*)d_in[5];
    const float* G3 = (const float*)d_in[6];
    float* out = (float*)d_out;

    // E (33.5 MB fp32, dead after rowselect) and CONTRIB (33.5 MB bf16) share
    // one region. GT2 aliases IDX+VAL (dead after scatter). GT1/GT3 in an
    // 8 MB arena at the end. Total footprint ~63 MB.
    char* ws = (char*)d_ws;
    float*          E       = (float*)ws;
    unsigned short* CONTRIB = (unsigned short*)ws;
    size_t o = (size_t)NB * NCEN * 4;                               // 33.5 MB
    int*   CNT   = (int*)(ws + o);   o += (size_t)NB * 4 * 4;       // 64 KB
    int*   IDX   = (int*)(ws + o);   o += (size_t)NB * 4 * CAP * 4; // 4 MB
    float* VAL   = (float*)(ws + o); o += (size_t)NB * 4 * CAP * 4; // 4 MB
    int*   FWD   = (int*)(ws + o);   o += (size_t)3 * NBCAP * 4;    // 3 MB
    int*   HIST2 = (int*)(ws + o);   o += (size_t)4 * NCH * SEG * 4;// 512 KB
    int*   CHOFF = (int*)(ws + o);   o += (size_t)4 * NCH * SEG * 4;// 512 KB
    int*   OFFS  = (int*)(ws + o);   o += 4 * SEG * 4;              // 8 KB
    int*   LEN   = (int*)(ws + o);   o += 4 * SEG * 4;              // 8 KB
    int*   Q     = (int*)(ws + o);   o += (size_t)4 * QMAX * 4;     // 74 KB
    int*   QCNT  = (int*)(ws + o);   o += 64;
    int*   BL    = (int*)(ws + o);   o += (size_t)3 * NBCAP * 4;    // 3 MB
    float* PV    = (float*)(ws + o); o += (size_t)3 * NBCAP * 4;    // 3 MB
    float* R0v   = (float*)(ws + o); o += (size_t)NB * RK * 4;      // 1 MB
    float* t1    = (float*)(ws + o); o += (size_t)NB * RK * 4;      // 1 MB
    float* t2    = (float*)(ws + o); o += (size_t)NB * RK * 4;      // 1 MB
    unsigned short* GT1 = (unsigned short*)(ws + o);
    o += (size_t)SEG * 2 * 64 * 64 * 2;                             // 8 MB arena

    unsigned short* GT2 = (unsigned short*)IDX;   // 8 MB: IDX+VAL, dead post-scatter
    unsigned short* GT3 = GT1;                    // 4 MB: GT1 dead after inv1

    e_gemm<<<dim3(NCEN / 64, NB / 64), 256, 0, stream>>>(X, C, LS, E, HIST2);
    rowselect<<<NB, 256, 0, stream>>>(E, G0, CNT, IDX, VAL, HIST2, R0v);
    scan2_split_kernel<<<4 + SEG, 256, 0, stream>>>(
        HIST2, OFFS, LEN, CHOFF, Q, QCNT, G1, GT1);
    scatter_kernel<<<dim3(NCH, 3), 256, 0, stream>>>(CNT, IDX, VAL, CHOFF, BL, PV, FWD);

    inv_stage_mfma<64><<<QMAX, 256, 0, stream>>>(
        R0v, GT1, Q + 1 * QMAX, QCNT + 1, LEN + SEG, OFFS + SEG,
        BL, PV, FWD, CONTRIB);
    gather_split_kernel<64, 64><<<NB / 4 + SEG, 256, 0, stream>>>(
        CNT, CONTRIB, t1, 1, G2, GT2);

    inv_stage_mfma<64><<<QMAX, 256, 0, stream>>>(
        t1, GT2, Q + 2 * QMAX, QCNT + 2, LEN + 2 * SEG, OFFS + 2 * SEG,
        BL + (size_t)NBCAP, PV + (size_t)NBCAP, FWD + (size_t)NBCAP, CONTRIB);
    gather_split_kernel<64, 32><<<NB / 4 + SEG, 256, 0, stream>>>(
        CNT, CONTRIB, t2, 2, G3, GT3);

    inv_stage_mfma<32><<<QMAX, 256, 0, stream>>>(
        t2, GT3, Q + 3 * QMAX, QCNT + 3, LEN + 3 * SEG, OFFS + 3 * SEG,
        BL + (size_t)2 * NBCAP, PV + (size_t)2 * NBCAP, FWD + (size_t)2 * NBCAP, CONTRIB);
    gather_kernel<32><<<NB / 4, 256, 0, stream>>>(CNT, CONTRIB, out, 3);
}